// Round 5
// baseline (351.418 us; speedup 1.0000x reference)
//
#include <hip/hip_runtime.h>

// 2D Haar DWT — persistent blocks + register-double-buffered software pipeline.
// x: (BC, 1024, 1024) fp32 -> out: [LL | LH | HL | HH], each (BC, 512, 512) fp32.
//   a=x[2i-1,2j-1] b=x[2i-1,2j] c=x[2i,2j-1] d=x[2i,2j]   (index -1 => 0)
//   LL=0.5(a+b+c+d) LH=0.5(c+d-a-b) HL=0.5((b-a)+(d-c)) HH=0.5((d-c)-(b-a))
//
// Work item w = (bc, i2): one row-pair of output (rows 2i2, 2i2+1), full width.
// Block handles ITERS consecutive items; item k+1's loads are issued BEFORE
// item k's shfl/compute/store, so the vmcnt wait on item k's data leaves
// item k+1's loads in flight (cross-item latency hiding — the thing the
// one-shot round-4 kernel lacked; its shfl forced a full vmcnt(0) drain
// with nothing else outstanding).
// All buffer indices static (named r0/r1 + unrolled loop): no scratch.

typedef float fx4 __attribute__((ext_vector_type(4)));
typedef float fx2 __attribute__((ext_vector_type(2)));

constexpr int ITERS = 6;   // 12288 items / 2048 blocks

struct Strip {
    fx4 vA, vB, vC, vD;    // input rows 4*i2-1 .. 4*i2+2, cols 4jp..4jp+3
    float pA, pB, pC, pD;  // lane-0 halo patches (col 4jp-1)
};

__device__ __forceinline__ void issue(const float* __restrict__ x, int wi,
                                      int c0, Strip& s)
{
    constexpr int W = 1024;
    const int i2 = wi & 255, bc = wi >> 8;
    const float* rB = x + ((long long)bc << 20) + (long long)(i2 << 2) * W + c0;
    const bool have_top = (i2 != 0);            // block-uniform

    s.vB = *(const fx4*)(rB);
    s.vC = *(const fx4*)(rB + W);
    s.vD = *(const fx4*)(rB + 2 * W);
    s.vA = fx4{0.f, 0.f, 0.f, 0.f};
    if (have_top) s.vA = *(const fx4*)(rB - W); // row 4*i2-1

    s.pA = s.pB = s.pC = s.pD = 0.f;
    if ((threadIdx.x & 63) == 0 && threadIdx.x != 0) { // wave lane 0, jp>0
        s.pB = rB[-1];
        s.pC = rB[W - 1];
        s.pD = rB[2 * W - 1];
        if (have_top) s.pA = rB[-W - 1];
    }
}

__device__ __forceinline__ void haar_row(float hT, fx4 vT, float hB, fx4 vB,
                                         fx2& ll, fx2& lh, fx2& hl, fx2& hh)
{
    // out col 2jp:   a=hT,   b=vT.x, c=hB,   d=vB.x
    // out col 2jp+1: a=vT.y, b=vT.z, c=vB.y, d=vB.z
    float st0 = hT + vT.x,   dt0 = vT.x - hT;
    float sb0 = hB + vB.x,   db0 = vB.x - hB;
    float st1 = vT.y + vT.z, dt1 = vT.z - vT.y;
    float sb1 = vB.y + vB.z, db1 = vB.z - vB.y;
    ll = fx2{0.5f * (st0 + sb0), 0.5f * (st1 + sb1)};
    lh = fx2{0.5f * (sb0 - st0), 0.5f * (sb1 - st1)};
    hl = fx2{0.5f * (dt0 + db0), 0.5f * (dt1 + db1)};
    hh = fx2{0.5f * (db0 - dt0), 0.5f * (db1 - dt1)};
}

__device__ __forceinline__ void process(float* __restrict__ out, long long S,
                                        int wi, int jp, const Strip& s)
{
    float hA = __shfl_up(s.vA.w, 1);
    float hB = __shfl_up(s.vB.w, 1);
    float hC = __shfl_up(s.vC.w, 1);
    float hD = __shfl_up(s.vD.w, 1);
    if ((threadIdx.x & 63) == 0) { hA = s.pA; hB = s.pB; hC = s.pC; hD = s.pD; }

    fx2 ll0, lh0, hl0, hh0, ll1, lh1, hl1, hh1;
    haar_row(hA, s.vA, hB, s.vB, ll0, lh0, hl0, hh0); // out row 2*i2
    haar_row(hC, s.vC, hD, s.vD, ll1, lh1, hl1, hh1); // out row 2*i2+1

    const int i2 = wi & 255, bc = wi >> 8;
    const long long obase0 = ((long long)bc * 512 + 2 * i2) * 512 + (jp << 1);
    const long long obase1 = obase0 + 512;

    __builtin_nontemporal_store(ll0, (fx2*)(out +         obase0));
    __builtin_nontemporal_store(lh0, (fx2*)(out +     S + obase0));
    __builtin_nontemporal_store(hl0, (fx2*)(out + 2 * S + obase0));
    __builtin_nontemporal_store(hh0, (fx2*)(out + 3 * S + obase0));
    __builtin_nontemporal_store(ll1, (fx2*)(out +         obase1));
    __builtin_nontemporal_store(lh1, (fx2*)(out +     S + obase1));
    __builtin_nontemporal_store(hl1, (fx2*)(out + 2 * S + obase1));
    __builtin_nontemporal_store(hh1, (fx2*)(out + 3 * S + obase1));
}

__global__ __launch_bounds__(256) void dwt_haar_kernel(
    const float* __restrict__ x, float* __restrict__ out, int n_bc)
{
    const long long S = (long long)n_bc * 512 * 512; // subband size (elements)
    const int wtot = n_bc * 256;                     // total work items
    const int jp = threadIdx.x;                      // col-pair 0..255
    const int c0 = jp << 2;                          // input col 4*jp
    const int w0 = blockIdx.x * ITERS;

    if (w0 >= wtot) return;

    Strip r0, r1;
    issue(x, w0, c0, r0);

#pragma unroll
    for (int it = 0; it < ITERS; ++it) {
        const int wi = w0 + it;
        if (wi >= wtot) break;                       // block-uniform
        if ((it & 1) == 0) {
            if (it + 1 < ITERS && wi + 1 < wtot) issue(x, wi + 1, c0, r1);
            process(out, S, wi, jp, r0);
        } else {
            if (it + 1 < ITERS && wi + 1 < wtot) issue(x, wi + 1, c0, r0);
            process(out, S, wi, jp, r1);
        }
    }
}

extern "C" void kernel_launch(void* const* d_in, const int* in_sizes, int n_in,
                              void* d_out, int out_size, void* d_ws, size_t ws_size,
                              hipStream_t stream) {
    const float* x = (const float*)d_in[0];
    float* out = (float*)d_out;

    const int n_bc = in_sizes[0] / (1024 * 1024);    // B*C = 48
    const int wtot = n_bc * 256;                     // 12288 row-pair items
    const int blocks = (wtot + ITERS - 1) / ITERS;   // 2048

    dwt_haar_kernel<<<blocks, 256, 0, stream>>>(x, out, n_bc);
}

// Round 6
// 332.053 us; speedup vs baseline: 1.0583x; 1.0583x over previous
//
#include <hip/hip_runtime.h>

// 2D Haar DWT, single fused pass, 2 output rows per thread.
// x: (BC, 1024, 1024) fp32 -> out: [LL | LH | HL | HH], each (BC, 512, 512) fp32.
// Per output pixel (i,j):
//   a=x[2i-1,2j-1] b=x[2i-1,2j] c=x[2i,2j-1] d=x[2i,2j]   (index -1 => 0)
//   LL=0.5(a+b+c+d) LH=0.5(c+d-a-b) HL=0.5((b-a)+(d-c)) HH=0.5((d-c)-(b-a))
// A/B vs round 3: ONLY change is non-temporal stores -> PLAIN float4 stores.
// Theory: NT forces the 196 MB write stream to drain to HBM inside the
// dispatch window; plain stores let L2/L3 absorb it (flush lands after
// kernel end; output is only read back later by the test).

typedef float fx4 __attribute__((ext_vector_type(4)));

__device__ __forceinline__ void haar_pair(const float t[9], const float b[9],
                                          fx4& ll, fx4& lh, fx4& hl, fx4& hh)
{
#pragma unroll
    for (int k = 0; k < 4; ++k) {
        float a = t[2 * k], bb = t[2 * k + 1];
        float c = b[2 * k], d  = b[2 * k + 1];
        float sum_t = a + bb, dif_t = bb - a;
        float sum_b = c + d,  dif_b = d - c;
        ll[k] = 0.5f * (sum_t + sum_b);
        lh[k] = 0.5f * (sum_b - sum_t);
        hl[k] = 0.5f * (dif_t + dif_b);
        hh[k] = 0.5f * (dif_b - dif_t);
    }
}

__global__ __launch_bounds__(256) void dwt_haar_kernel(
    const float* __restrict__ x, float* __restrict__ out, int n_bc)
{
    constexpr int W  = 1024;   // input width
    constexpr int Ho = 512;    // output height
    constexpr int Wo = 512;    // output width

    const long long S = (long long)n_bc * Ho * Wo; // subband size (elements)

    int g   = blockIdx.x * 256 + threadIdx.x;
    int j4  = g & 127;             // col group within row (128 per row)
    int rem = g >> 7;
    int i2  = rem & 255;           // row-pair index: out rows 2*i2, 2*i2+1
    int bc  = rem >> 8;            // image plane

    const int c0 = j4 << 3;        // input col 8*j4
    // input row 4*i2 (bottom row of first output row), at col c0
    const float* r1 = x + ((long long)bc * 1024 + 4 * i2) * W + c0;

    // ---- issue all vector loads up-front (independent, max MLP) ----
    float4 v1a = *(const float4*)(r1);
    float4 v1b = *(const float4*)(r1 + 4);
    float4 v2a = *(const float4*)(r1 + W);
    float4 v2b = *(const float4*)(r1 + W + 4);
    float4 v3a = *(const float4*)(r1 + 2 * W);
    float4 v3b = *(const float4*)(r1 + 2 * W + 4);
    float4 v0a, v0b;
    const bool have_top = (i2 > 0);      // wave-uniform
    if (have_top) {                      // input row 4*i2-1
        v0a = *(const float4*)(r1 - W);
        v0b = *(const float4*)(r1 - W + 4);
    } else {
        v0a = make_float4(0.f, 0.f, 0.f, 0.f);
        v0b = v0a;
    }

    // halo col 8*j4-1 for each of the 4 input rows (L1 hits; zero-pad at -1)
    float h0 = 0.f, h1 = 0.f, h2 = 0.f, h3 = 0.f;
    if (j4 > 0) {
        h1 = r1[-1];
        h2 = r1[W - 1];
        h3 = r1[2 * W - 1];
        if (have_top) h0 = r1[-W - 1];
    }

    // ---- assemble 9-wide windows ----
    float w0[9], w1[9], w2[9], w3[9];
    w0[0] = h0; w0[1] = v0a.x; w0[2] = v0a.y; w0[3] = v0a.z; w0[4] = v0a.w;
                w0[5] = v0b.x; w0[6] = v0b.y; w0[7] = v0b.z; w0[8] = v0b.w;
    w1[0] = h1; w1[1] = v1a.x; w1[2] = v1a.y; w1[3] = v1a.z; w1[4] = v1a.w;
                w1[5] = v1b.x; w1[6] = v1b.y; w1[7] = v1b.z; w1[8] = v1b.w;
    w2[0] = h2; w2[1] = v2a.x; w2[2] = v2a.y; w2[3] = v2a.z; w2[4] = v2a.w;
                w2[5] = v2b.x; w2[6] = v2b.y; w2[7] = v2b.z; w2[8] = v2b.w;
    w3[0] = h3; w3[1] = v3a.x; w3[2] = v3a.y; w3[3] = v3a.z; w3[4] = v3a.w;
                w3[5] = v3b.x; w3[6] = v3b.y; w3[7] = v3b.z; w3[8] = v3b.w;

    // ---- compute both output rows ----
    fx4 ll0, lh0, hl0, hh0, ll1, lh1, hl1, hh1;
    haar_pair(w0, w1, ll0, lh0, hl0, hh0);   // out row 2*i2   (top=4i2-1, bot=4i2)
    haar_pair(w2, w3, ll1, lh1, hl1, hh1);   // out row 2*i2+1 (top=4i2+1, bot=4i2+2)

    // ---- PLAIN float4 stores (L2/L3 write-back absorbs; flush after kernel) ----
    const long long obase0 = ((long long)bc * Ho + 2 * i2) * Wo + (j4 << 2);
    const long long obase1 = obase0 + Wo;

    *(fx4*)(out +         obase0) = ll0;
    *(fx4*)(out +     S + obase0) = lh0;
    *(fx4*)(out + 2 * S + obase0) = hl0;
    *(fx4*)(out + 3 * S + obase0) = hh0;
    *(fx4*)(out +         obase1) = ll1;
    *(fx4*)(out +     S + obase1) = lh1;
    *(fx4*)(out + 2 * S + obase1) = hl1;
    *(fx4*)(out + 3 * S + obase1) = hh1;
}

extern "C" void kernel_launch(void* const* d_in, const int* in_sizes, int n_in,
                              void* d_out, int out_size, void* d_ws, size_t ws_size,
                              hipStream_t stream) {
    const float* x = (const float*)d_in[0];
    float* out = (float*)d_out;

    const int n_bc = in_sizes[0] / (1024 * 1024);              // B*C = 48
    // one thread per (plane, row-pair, col-group): 48 * 256 * 128
    const long long total_threads = (long long)n_bc * 256 * 128;
    const int blocks = (int)(total_threads / 256);             // 6144

    dwt_haar_kernel<<<blocks, 256, 0, stream>>>(x, out, n_bc);
}